// Round 13
// baseline (156.479 us; speedup 1.0000x reference)
//
#include <hip/hip_runtime.h>
#include <hip/hip_bf16.h>

#define DDIM 128
#define RDIM 32
#define PBLK 256    // prep-kernel block size
#define BLK  512    // fused kernel: 8 waves
#define CAP  160    // graph rows cached in LDS (bf16); overflow recomputed
#define XS2  136    // x2s row stride u16 (272 B -> 2-way max bank aliasing)
#define HSTR 40     // hs row stride u16

typedef __attribute__((ext_vector_type(8))) short bf16x8;
typedef __attribute__((ext_vector_type(4))) float f32x4;

__device__ __forceinline__ float tanh_fast(float v) {
  float e = __expf(2.f * v);
  return 1.f - 2.f / (e + 1.f);
}
__device__ __forceinline__ float sigmoid_fast(float v) {
  return 1.f / (1.f + __expf(-v));
}
__device__ __forceinline__ unsigned short f2bf(float f) {  // RNE f32->bf16
  unsigned u = __float_as_uint(f);
  u += 0x7fffu + ((u >> 16) & 1u);
  return (unsigned short)(u >> 16);
}
__device__ __forceinline__ float bf2f(unsigned short s) {
  return __uint_as_float(((unsigned)s) << 16);
}
__device__ __forceinline__ unsigned pkbf(float lo, float hi) {  // v_cvt_pk_bf16_f32
  __hip_bfloat162 t2 = __float22bfloat162_rn(make_float2(lo, hi));
  return *reinterpret_cast<unsigned*>(&t2);
}
__device__ __forceinline__ int lower_bound(const int* __restrict__ b, int n, int v) {
  int lo = 0, hi = n;
  while (lo < hi) { int m = (lo + hi) >> 1; if (b[m] < v) lo = m + 1; else hi = m; }
  return lo;
}

// ---------------------------------------------------------------------------
// K0: build bf16 A-fragments of W1^T and W2^T (transposed-GEMM).
//   w1tf[frag=mt2*4+kk][lane][8] : W1^T[r=mt2*16+lr][d=kk*32+q*8+j]
//   w2tf[mt][lane][8]            : W2^T[d=mt*16+lr][r=q*8+j]
// A-frag layout (16x16x32): row=l&15, k=(l>>4)*8+j.
// ---------------------------------------------------------------------------
__global__ void k0_prep(const float* __restrict__ w1, const float* __restrict__ w2,
                        unsigned short* __restrict__ w1tf, unsigned short* __restrict__ w2tf)
{
  const int i  = blockIdx.x * blockDim.x + threadIdx.x;   // 0..1023
  const int l  = i & 63;
  const int lr = l & 15, q = l >> 4;
  if (i < 512) {
    const int frag = i >> 6;             // mt2*4+kk
    const int mt2 = frag >> 2, kk = frag & 3;
    bf16x8 v;
    #pragma unroll
    for (int j = 0; j < 8; ++j)
      v[j] = (short)f2bf(w1[(size_t)(kk * 32 + q * 8 + j) * RDIM + mt2 * 16 + lr]);
    *(bf16x8*)&w1tf[(size_t)i * 8] = v;
  } else {
    const int mt = (i - 512) >> 6;
    bf16x8 v;
    #pragma unroll
    for (int j = 0; j < 8; ++j)
      v[j] = (short)f2bf(w2[(size_t)(q * 8 + j) * DDIM + mt * 16 + lr]);
    *(bf16x8*)&w2tf[(size_t)(i - 512) * 8] = v;
  }
}

// ---------------------------------------------------------------------------
// KB: parallel per-graph bounds precompute.
// ---------------------------------------------------------------------------
__global__ void kb_bounds(const int* __restrict__ batch, int* __restrict__ bounds,
                          int N, int G)
{
  const int g = blockIdx.x * blockDim.x + threadIdx.x;
  if (g <= G) bounds[g] = lower_bound(batch, N, g);
}

// ---------------------------------------------------------------------------
// K_FUSED v2: one block (8 waves) per graph.
// Pass1: MLP gate over graph rows (transposed MFMA), x2 -> LDS (CAP rows) +
// register mean accumulate. Mean -> tg = tanh(mean@W) (coalesced parallel
// GEMV). Pass2: coef = sigmoid(x2.tg), out = sum coef*x2 from LDS; overflow
// rows recomputed. x read once from HBM; x2 never touches HBM.
// ---------------------------------------------------------------------------
__global__ __launch_bounds__(BLK, 4) void k_fused(
    const float* __restrict__ x,
    const unsigned short* __restrict__ w1tf, const float* __restrict__ b1,
    const unsigned short* __restrict__ w2tf, const float* __restrict__ b2,
    const float* __restrict__ W, const int* __restrict__ bounds,
    float* __restrict__ out, int N)
{
  __shared__ unsigned short w1t[512 * 8];        //  8,192 B
  __shared__ unsigned short w2t[512 * 8];        //  8,192 B
  __shared__ unsigned short x2s[CAP * XS2];      // 43,520 B
  __shared__ unsigned short hs8[8][16 * HSTR];   // 10,240 B
  __shared__ float part[8][132];                 //  4,224 B
  __shared__ float meanv[DDIM];                  //    512 B
  __shared__ float tgs[DDIM];                    //    512 B  (total 75,392)

  const int t  = threadIdx.x;
  const int l  = t & 63;
  const int w  = t >> 6;          // wave 0..7
  const int lr = l & 15;
  const int q  = l >> 4;
  const int g  = blockIdx.x;
  const int lo = bounds[g], hi = bounds[g + 1];
  const int cnt = hi - lo;
  unsigned short* hs = hs8[w];

  // ---- stage weight fragments to LDS (one copy serves 8 waves) ----
  for (int i = t; i < 512; i += BLK) {
    ((bf16x8*)w1t)[i] = ((const bf16x8*)w1tf)[i];
    ((bf16x8*)w2t)[i] = ((const bf16x8*)w2tf)[i];
  }
  __syncthreads();

  // ---- MLP core for a 16-row tile: cacc[mt][c] = A2^T col=row, +b2 ----
  auto core = [&](int tb, f32x4 (&cacc)[8]) -> const float* {
    const int ridx = tb + lr;
    const int rcl  = min(ridx, cnt - 1);
    const float* xrow = x + (size_t)(lo + rcl) * DDIM;
    bf16x8 xf[4];
    #pragma unroll
    for (int kk = 0; kk < 4; ++kk) {
      float4 a = *(const float4*)(xrow + kk * 32 + q * 8);
      float4 b = *(const float4*)(xrow + kk * 32 + q * 8 + 4);
      uint4 u;
      u.x = pkbf(a.x, a.y); u.y = pkbf(a.z, a.w);
      u.z = pkbf(b.x, b.y); u.w = pkbf(b.z, b.w);
      xf[kk] = *(bf16x8*)&u;
    }
    f32x4 hacc[2];
    {
      float4 bv0 = *(const float4*)(b1 + q * 4);
      float4 bv1 = *(const float4*)(b1 + 16 + q * 4);
      hacc[0][0] = bv0.x; hacc[0][1] = bv0.y; hacc[0][2] = bv0.z; hacc[0][3] = bv0.w;
      hacc[1][0] = bv1.x; hacc[1][1] = bv1.y; hacc[1][2] = bv1.z; hacc[1][3] = bv1.w;
    }
    #pragma unroll
    for (int kk = 0; kk < 4; ++kk) {
      bf16x8 wa = *(const bf16x8*)&w1t[(size_t)((0 * 4 + kk) * 64 + l) * 8];
      bf16x8 wb = *(const bf16x8*)&w1t[(size_t)((1 * 4 + kk) * 64 + l) * 8];
      hacc[0] = __builtin_amdgcn_mfma_f32_16x16x32_bf16(wa, xf[kk], hacc[0], 0, 0, 0);
      hacc[1] = __builtin_amdgcn_mfma_f32_16x16x32_bf16(wb, xf[kk], hacc[1], 0, 0, 0);
    }
    #pragma unroll
    for (int mt2 = 0; mt2 < 2; ++mt2) {
      float h0 = fmaxf(hacc[mt2][0], 0.f), h1 = fmaxf(hacc[mt2][1], 0.f);
      float h2 = fmaxf(hacc[mt2][2], 0.f), h3 = fmaxf(hacc[mt2][3], 0.f);
      uint2 p; p.x = pkbf(h0, h1); p.y = pkbf(h2, h3);
      *(uint2*)&hs[lr * HSTR + mt2 * 16 + q * 4] = p;
    }
    bf16x8 ah = *(const bf16x8*)&hs[lr * HSTR + q * 8];   // col=node, k=r
    #pragma unroll
    for (int mt = 0; mt < 8; ++mt) {
      float4 bv = *(const float4*)(b2 + mt * 16 + q * 4);
      cacc[mt][0] = bv.x; cacc[mt][1] = bv.y; cacc[mt][2] = bv.z; cacc[mt][3] = bv.w;
    }
    #pragma unroll
    for (int mt = 0; mt < 8; ++mt) {
      bf16x8 wf = *(const bf16x8*)&w2t[(size_t)(mt * 64 + l) * 8];
      cacc[mt] = __builtin_amdgcn_mfma_f32_16x16x32_bf16(wf, ah, cacc[mt], 0, 0, 0);
    }
    return xrow;
  };

  // ---- PASS 1: MLP, cache to LDS, accumulate mean ----
  float macc[8][4];
  #pragma unroll
  for (int mt = 0; mt < 8; ++mt)
    #pragma unroll
    for (int c = 0; c < 4; ++c) macc[mt][c] = 0.f;

  const int niter1 = (cnt + 127) >> 7;
  for (int it = 0; it < niter1; ++it) {
    const int tb = it * 128 + w * 16;
    if (tb >= cnt) continue;
    f32x4 cacc[8];
    const float* xrow = core(tb, cacc);
    const int ridx = tb + lr;
    if (ridx < cnt) {
      #pragma unroll
      for (int mt = 0; mt < 8; ++mt) {
        float4 xg = *(const float4*)(xrow + mt * 16 + q * 4);   // L1-hot
        float y0 = xg.x * (1.f + tanh_fast(cacc[mt][0]));
        float y1 = xg.y * (1.f + tanh_fast(cacc[mt][1]));
        float y2 = xg.z * (1.f + tanh_fast(cacc[mt][2]));
        float y3 = xg.w * (1.f + tanh_fast(cacc[mt][3]));
        macc[mt][0] += y0; macc[mt][1] += y1;
        macc[mt][2] += y2; macc[mt][3] += y3;
        if (ridx < CAP) {
          uint2 p; p.x = pkbf(y0, y1); p.y = pkbf(y2, y3);
          *(uint2*)&x2s[ridx * XS2 + mt * 16 + q * 4] = p;
        }
      }
    }
  }
  __syncthreads();

  // ---- mean: reduce macc over lr lanes, cross-wave via part ----
  #pragma unroll
  for (int mt = 0; mt < 8; ++mt)
    #pragma unroll
    for (int c = 0; c < 4; ++c) {
      float v = macc[mt][c];
      v += __shfl_xor(v, 1, 64);
      v += __shfl_xor(v, 2, 64);
      v += __shfl_xor(v, 4, 64);
      v += __shfl_xor(v, 8, 64);
      macc[mt][c] = v;
    }
  if (lr == 0) {
    #pragma unroll
    for (int mt = 0; mt < 8; ++mt)
      *(float4*)&part[w][mt * 16 + q * 4] =
          make_float4(macc[mt][0], macc[mt][1], macc[mt][2], macc[mt][3]);
  }
  __syncthreads();
  if (t < DDIM) {
    float m = 0.f;
    #pragma unroll
    for (int w2 = 0; w2 < 8; ++w2) m += part[w2][t];
    meanv[t] = (cnt > 0) ? m / (float)cnt : 0.f;
  }
  __syncthreads();

  // ---- tg = tanh(mean @ W): coalesced parallel GEMV (4 thr/col x 32 k) ----
  {
    const int c = t & 127, s = t >> 7;    // s = 0..3
    float a = 0.f;
    #pragma unroll
    for (int k = 0; k < 32; ++k)
      a = fmaf(meanv[s * 32 + k], W[(size_t)(s * 32 + k) * DDIM + c], a);
    part[s][c] = a;
  }
  __syncthreads();
  if (t < DDIM)
    tgs[t] = tanh_fast(part[0][t] + part[1][t] + part[2][t] + part[3][t]);
  __syncthreads();

  // ---- PASS 2a: cached rows from LDS ----
  float oacc[8][4];
  #pragma unroll
  for (int mt = 0; mt < 8; ++mt)
    #pragma unroll
    for (int c = 0; c < 4; ++c) oacc[mt][c] = 0.f;

  const int cap2 = cnt < CAP ? cnt : CAP;
  const int niter2 = (cap2 + 127) >> 7;
  for (int it = 0; it < niter2; ++it) {
    const int tb = it * 128 + w * 16;
    if (tb >= cap2) continue;
    const int ridx = tb + lr;
    const bool v = ridx < cap2;
    const int rr = v ? ridx : 0;
    float xv[8][4];
    float p = 0.f;
    #pragma unroll
    for (int mt = 0; mt < 8; ++mt) {
      uint2 u = *(const uint2*)&x2s[rr * XS2 + mt * 16 + q * 4];
      xv[mt][0] = bf2f((unsigned short)(u.x & 0xffffu));
      xv[mt][1] = bf2f((unsigned short)(u.x >> 16));
      xv[mt][2] = bf2f((unsigned short)(u.y & 0xffffu));
      xv[mt][3] = bf2f((unsigned short)(u.y >> 16));
      float4 tg4 = *(const float4*)&tgs[mt * 16 + q * 4];
      p = fmaf(xv[mt][0], tg4.x, p); p = fmaf(xv[mt][1], tg4.y, p);
      p = fmaf(xv[mt][2], tg4.z, p); p = fmaf(xv[mt][3], tg4.w, p);
    }
    p += __shfl_xor(p, 16, 64);
    p += __shfl_xor(p, 32, 64);
    const float coef = sigmoid_fast(p);
    if (v) {
      #pragma unroll
      for (int mt = 0; mt < 8; ++mt)
        #pragma unroll
        for (int c = 0; c < 4; ++c) oacc[mt][c] = fmaf(coef, xv[mt][c], oacc[mt][c]);
    }
  }

  // ---- PASS 2b: overflow rows (>= CAP) recomputed ----
  if (cnt > CAP) {
    const int niter3 = (cnt - CAP + 127) >> 7;
    for (int it = 0; it < niter3; ++it) {
      const int tb = CAP + it * 128 + w * 16;
      if (tb >= cnt) continue;
      f32x4 cacc[8];
      const float* xrow = core(tb, cacc);
      const int ridx = tb + lr;
      const bool v = ridx < cnt;
      float p = 0.f;
      uint2 y2[8];
      #pragma unroll
      for (int mt = 0; mt < 8; ++mt) {
        float4 xg = *(const float4*)(xrow + mt * 16 + q * 4);
        float y0 = xg.x * (1.f + tanh_fast(cacc[mt][0]));
        float y1 = xg.y * (1.f + tanh_fast(cacc[mt][1]));
        float y2v = xg.z * (1.f + tanh_fast(cacc[mt][2]));
        float y3 = xg.w * (1.f + tanh_fast(cacc[mt][3]));
        float4 tg4 = *(const float4*)&tgs[mt * 16 + q * 4];
        p = fmaf(y0, tg4.x, p); p = fmaf(y1, tg4.y, p);
        p = fmaf(y2v, tg4.z, p); p = fmaf(y3, tg4.w, p);
        y2[mt].x = pkbf(y0, y1); y2[mt].y = pkbf(y2v, y3);
      }
      p += __shfl_xor(p, 16, 64);
      p += __shfl_xor(p, 32, 64);
      const float coef = sigmoid_fast(p);
      if (v) {
        #pragma unroll
        for (int mt = 0; mt < 8; ++mt) {
          oacc[mt][0] = fmaf(coef, bf2f((unsigned short)(y2[mt].x & 0xffffu)), oacc[mt][0]);
          oacc[mt][1] = fmaf(coef, bf2f((unsigned short)(y2[mt].x >> 16)),     oacc[mt][1]);
          oacc[mt][2] = fmaf(coef, bf2f((unsigned short)(y2[mt].y & 0xffffu)), oacc[mt][2]);
          oacc[mt][3] = fmaf(coef, bf2f((unsigned short)(y2[mt].y >> 16)),     oacc[mt][3]);
        }
      }
    }
  }
  __syncthreads();

  // ---- out: reduce oacc over lr lanes, cross-wave via part ----
  #pragma unroll
  for (int mt = 0; mt < 8; ++mt)
    #pragma unroll
    for (int c = 0; c < 4; ++c) {
      float v = oacc[mt][c];
      v += __shfl_xor(v, 1, 64);
      v += __shfl_xor(v, 2, 64);
      v += __shfl_xor(v, 4, 64);
      v += __shfl_xor(v, 8, 64);
      oacc[mt][c] = v;
    }
  if (lr == 0) {
    #pragma unroll
    for (int mt = 0; mt < 8; ++mt)
      *(float4*)&part[w][mt * 16 + q * 4] =
          make_float4(oacc[mt][0], oacc[mt][1], oacc[mt][2], oacc[mt][3]);
  }
  __syncthreads();
  if (t < DDIM) {
    float m = 0.f;
    #pragma unroll
    for (int w2 = 0; w2 < 8; ++w2) m += part[w2][t];
    out[(size_t)g * DDIM + t] = m;
  }
}

// ---------------------------------------------------------------------------
extern "C" void kernel_launch(void* const* d_in, const int* in_sizes, int n_in,
                              void* d_out, int out_size, void* d_ws, size_t ws_size,
                              hipStream_t stream) {
  const float* x     = (const float*)d_in[0];
  const int*   batch = (const int*)d_in[1];
  const float* w1 = (const float*)d_in[3];
  const float* b1 = (const float*)d_in[4];
  const float* w2 = (const float*)d_in[5];
  const float* b2 = (const float*)d_in[6];
  const float* W  = (const float*)d_in[7];
  float* out = (float*)d_out;

  const int N = in_sizes[0] / DDIM;
  const int G = out_size / DDIM;

  // ws layout: [w1tf 4096 u16][w2tf 4096 u16][bounds G+1 int]
  unsigned short* w1tf = (unsigned short*)d_ws;
  unsigned short* w2tf = w1tf + 4096;
  int* bounds = (int*)(w2tf + 4096);
  (void)ws_size; (void)n_in;

  hipLaunchKernelGGL(k0_prep, dim3(4), dim3(PBLK), 0, stream, w1, w2, w1tf, w2tf);
  hipLaunchKernelGGL(kb_bounds, dim3((G + 1 + PBLK - 1) / PBLK), dim3(PBLK), 0, stream,
                     batch, bounds, N, G);
  hipLaunchKernelGGL(k_fused, dim3(G), dim3(BLK), 0, stream,
                     x, w1tf, b1, w2tf, b2, W, bounds, out, N);
}